// Round 4
// baseline (7555.839 us; speedup 1.0000x reference)
//
#include <hip/hip_runtime.h>
#include <hip/hip_bf16.h>
#include <math.h>

// Problem constants
#define B_     32
#define S_     2048
#define E_     300
#define H_     256
#define STEPS_ 24
#define BS_    (B_ * S_)      // 65536
#define NPACK  1280           // 5 gates * 256
#define KSL    16             // 512/32 k-slabs
#define KSLP   10             // 320/32 (proj K padded)

typedef __bf16 bf16x8 __attribute__((ext_vector_type(8)));
typedef float  f32x4  __attribute__((ext_vector_type(4)));

__device__ __forceinline__ float sigm(float x) {
    return 1.0f / (1.0f + __expf(-x));
}
__device__ __forceinline__ float fast_tanh(float x) {
    return 2.0f * sigm(2.0f * x) - 1.0f;
}

// ---------------------------------------------------------------------------
// Pack step-GEMM B: Bp[ks][p][kin], p = w*80 + g*16 + c_lo, col c = w*16+c_lo.
// k<256 -> U_*_l[k], k>=256 -> U_*_r[k-256]. Gates: 0=i,1=o,2=u,3=f_l,4=f_r.
// ---------------------------------------------------------------------------
__global__ __launch_bounds__(256) void pack_B_kernel(
    const float* __restrict__ U_iou_l, const float* __restrict__ U_iou_r,
    const float* __restrict__ U_f_ll,  const float* __restrict__ U_f_lr,
    const float* __restrict__ U_f_rl,  const float* __restrict__ U_f_rr,
    __hip_bfloat16* __restrict__ Bp)
{
    const int idx = blockIdx.x * 256 + threadIdx.x;      // 16*1280*32 = 655360
    if (idx >= KSL * NPACK * 32) return;
    const int ks = idx / (NPACK * 32);
    const int rem = idx - ks * (NPACK * 32);
    const int p = rem >> 5;
    const int kin = rem & 31;
    const int k = ks * 32 + kin;
    const int w = p / 80;
    const int rg = p - w * 80;
    const int g = rg >> 4;
    const int c = w * 16 + (rg & 15);
    float v;
    if (g < 3) {
        const int col = g * 256 + c;
        v = (k < 256) ? U_iou_l[k * 768 + col] : U_iou_r[(k - 256) * 768 + col];
    } else if (g == 3) {
        v = (k < 256) ? U_f_ll[k * 256 + c] : U_f_lr[(k - 256) * 256 + c];
    } else {
        v = (k < 256) ? U_f_rl[k * 256 + c] : U_f_rr[(k - 256) * 256 + c];
    }
    Bp[idx] = __float2bfloat16(v);
}

// ---------------------------------------------------------------------------
// Pack projection weights for gate-interleaved output:
// Wp[ks][p][kin]; p = cw*64 + g*16 + c_lo; col = cw*16+c_lo;
// g in {0=i,1=o,2=u,3=f}. k>=300 zero-padded.
// ---------------------------------------------------------------------------
__global__ __launch_bounds__(256) void pack_W_kernel(
    const float* __restrict__ W_iou, const float* __restrict__ W_f,
    __hip_bfloat16* __restrict__ Wp)
{
    const int idx = blockIdx.x * 256 + threadIdx.x;      // 10*1024*32 = 327680
    if (idx >= KSLP * 1024 * 32) return;
    const int ks = idx / (1024 * 32);
    const int rem = idx - ks * (1024 * 32);
    const int p = rem >> 5;
    const int kin = rem & 31;
    const int k = ks * 32 + kin;
    const int cw = p >> 6;
    const int g = (p >> 4) & 3;
    const int col = cw * 16 + (p & 15);
    float v = 0.f;
    if (k < E_) v = (g < 3) ? W_iou[k * 768 + g * 256 + col] : W_f[k * 256 + col];
    Wp[idx] = __float2bfloat16(v);
}

// ---------------------------------------------------------------------------
// Winner: winner[t][b][d] = max s with tree_ids[b][t][s]==d (last-wins scatter)
// ---------------------------------------------------------------------------
__global__ __launch_bounds__(256) void winner_kernel(
    const int* __restrict__ tree_ids, int* __restrict__ winner)
{
    const int idx = blockIdx.x * 256 + threadIdx.x;
    if (idx >= B_ * STEPS_ * S_) return;
    const int b = idx / (STEPS_ * S_);
    const int rem = idx - b * (STEPS_ * S_);
    const int t = rem / S_;
    const int s = rem - t * S_;
    const int d = tree_ids[idx];
    if ((unsigned)d < (unsigned)S_)
        atomicMax(&winner[(size_t)t * BS_ + b * S_ + d], s);
}

// ---------------------------------------------------------------------------
// Projection GEMM (MFMA): writes gate-interleaved x_pack[row][256 cols][4 g]
// (bf16, 1024 elems/row). Block: 256 thr, M=16, K=320. Wave owns h-cols
// [wave*64, wave*64+64) x 4 gates = 16 N-tiles (nt = chunk*4 + g).
// ---------------------------------------------------------------------------
__global__ __launch_bounds__(256) void proj_kernel(
    const float* __restrict__ input, const __hip_bfloat16* __restrict__ Wp,
    const float* __restrict__ b_iou, const float* __restrict__ b_f,
    __hip_bfloat16* __restrict__ x_pack)
{
    __shared__ __hip_bfloat16 Ash[16][328];              // +8 pad
    const int tid = threadIdx.x;
    const int row0 = blockIdx.x * 16;

    // Stage A: fp32 -> bf16, 16 rows x 320 (zeros past 300)
    for (int it = 0; it < 5; ++it) {
        const int idx = tid + it * 256;                  // 16 rows * 80 chunks
        const int r = idx / 80;
        const int c4 = idx - r * 80;
        float4 v = make_float4(0.f, 0.f, 0.f, 0.f);
        if (c4 < 75) v = *(const float4*)(input + (size_t)(row0 + r) * E_ + c4 * 4);
        union { __hip_bfloat16 h[4]; uint2 u; } tconv;
        tconv.h[0] = __float2bfloat16(v.x);
        tconv.h[1] = __float2bfloat16(v.y);
        tconv.h[2] = __float2bfloat16(v.z);
        tconv.h[3] = __float2bfloat16(v.w);
        *(uint2*)&Ash[r][c4 * 4] = tconv.u;
    }
    __syncthreads();

    const int lane = tid & 63;
    const int wave = tid >> 6;
    const int m16 = lane & 15;
    const int q = lane >> 4;

    f32x4 acc[16];
    const f32x4 z4 = {0.f, 0.f, 0.f, 0.f};
#pragma unroll
    for (int nt = 0; nt < 16; ++nt) acc[nt] = z4;

    const __hip_bfloat16* wp = Wp + ((size_t)(wave * 256 + m16)) * 32 + q * 8;
    for (int ks = 0; ks < KSLP; ++ks) {
        const bf16x8 a = *reinterpret_cast<const bf16x8*>(&Ash[m16][ks * 32 + q * 8]);
        const __hip_bfloat16* wk = wp + (size_t)ks * 32768;
#pragma unroll
        for (int nt = 0; nt < 16; ++nt) {
            const bf16x8 bb = *reinterpret_cast<const bf16x8*>(wk + nt * 512);
            acc[nt] = __builtin_amdgcn_mfma_f32_16x16x32_bf16(a, bb, acc[nt], 0, 0, 0);
        }
    }

    // Epilogue: 4 gates per (row, col) live in this thread -> one uint2 store
#pragma unroll
    for (int j = 0; j < 4; ++j) {
        const int row = row0 + q * 4 + j;
        const size_t xrow = (size_t)row * 1024;
#pragma unroll
        for (int chunk = 0; chunk < 4; ++chunk) {
            const int c = (wave * 4 + chunk) * 16 + m16;   // h-col
            union { __hip_bfloat16 h[4]; uint2 u; } pk;
            pk.h[0] = __float2bfloat16(acc[chunk * 4 + 0][j] + b_iou[c]);
            pk.h[1] = __float2bfloat16(acc[chunk * 4 + 1][j] + b_iou[256 + c]);
            pk.h[2] = __float2bfloat16(acc[chunk * 4 + 2][j] + b_iou[512 + c]);
            pk.h[3] = __float2bfloat16(acc[chunk * 4 + 3][j] + b_f[c]);
            *(uint2*)(x_pack + xrow + (size_t)c * 4) = pk.u;
        }
    }
}

// ---------------------------------------------------------------------------
// Copy-through + null-slot zero. Each thread: 4 consecutive uint4 chunks of
// h and c (64B each), one winner read. idx4 over BS*8.
// ---------------------------------------------------------------------------
__global__ __launch_bounds__(256) void copy_kernel(
    const uint4* __restrict__ h_cur4, uint4* __restrict__ h_next4,
    const uint4* __restrict__ c_cur4, uint4* __restrict__ c_next4,
    const int* __restrict__ winner_t)
{
    const int idx4 = blockIdx.x * 256 + threadIdx.x;     // BS*8
    const int row = idx4 >> 3;
    const int base = idx4 * 4;
    const int d = row & (S_ - 1);
    if (d == 0) {
        const uint4 z = make_uint4(0u, 0u, 0u, 0u);
#pragma unroll
        for (int k = 0; k < 4; ++k) { h_next4[base + k] = z; c_next4[base + k] = z; }
    } else if (winner_t[row] < 0) {
        uint4 hv[4], cv[4];
#pragma unroll
        for (int k = 0; k < 4; ++k) { hv[k] = h_cur4[base + k]; cv[k] = c_cur4[base + k]; }
#pragma unroll
        for (int k = 0; k < 4; ++k) { h_next4[base + k] = hv[k]; c_next4[base + k] = cv[k]; }
    }
}

// ---------------------------------------------------------------------------
// Fused MFMA step. Block: 256 thr (4 waves), M=32 rows.
// Staging: h_l|h_r (32x512 bf16) AND c_l,c_r (32x256 bf16 each) -> LDS in one
// batched coalesced phase. K-loop: B frags from global (L2-resident).
// Epilogue: batched winner prefetch + per-wg batched unconditional x loads
// (raises outstanding-miss count; winner gating only on compute/stores).
// ---------------------------------------------------------------------------
__global__ __launch_bounds__(256, 2) void step_kernel(
    const __hip_bfloat16* __restrict__ h_cur, const __hip_bfloat16* __restrict__ c_cur,
    __hip_bfloat16* __restrict__ h_next, __hip_bfloat16* __restrict__ c_next,
    const int* __restrict__ tree_ids, const int* __restrict__ tree_ids_l,
    const int* __restrict__ tree_ids_r, const int* __restrict__ winner_t,
    const __hip_bfloat16* __restrict__ x_pack,
    const __hip_bfloat16* __restrict__ Bp, int t)
{
    const int b = blockIdx.x >> 6;            // 64 tiles of 32 rows per batch
    const int tile = blockIdx.x & 63;
    const int s0 = tile * 32;
    const int tid = threadIdx.x;

    __shared__ __hip_bfloat16 Ash[32][520];    // 32 x (512 + 8 pad) = 33.3 KB
    __shared__ __hip_bfloat16 Csh[2][32][264]; // c_l/c_r tiles, +8 pad = 33.8 KB
    __shared__ int sIdl[32], sIdr[32], sIdd[32];

    const int* idd_b = tree_ids   + ((size_t)b * STEPS_ + t) * S_;
    const int* idl_b = tree_ids_l + ((size_t)b * STEPS_ + t) * S_;
    const int* idr_b = tree_ids_r + ((size_t)b * STEPS_ + t) * S_;

    if (tid < 32)       sIdl[tid]      = idl_b[s0 + tid];
    else if (tid < 64)  sIdr[tid - 32] = idr_b[s0 + tid - 32];
    else if (tid < 96)  sIdd[tid - 64] = idd_b[s0 + tid - 64];
    __syncthreads();

    // Batched staging: h (2048 chunks) + c_l/c_r (2048 chunks), 16B each
#pragma unroll
    for (int it = 0; it < 16; ++it) {
        const int idx = tid + it * 256;        // 0..4095
        if (idx < 2048) {
            const int r = idx >> 6;            // 64 chunks per h row
            const int ch = idx & 63;
            const int half = ch >> 5;
            const int c16 = ch & 31;
            const int src = half ? sIdr[r] : sIdl[r];
            const uint4 v = *(const uint4*)(h_cur + ((size_t)(b * S_) + src) * H_ + c16 * 8);
            *(uint4*)&Ash[r][half * 256 + c16 * 8] = v;
        } else {
            const int idx2 = idx - 2048;
            const int r = idx2 >> 6;           // 64 chunks: 2 halves x 32
            const int ch = idx2 & 63;
            const int half = ch >> 5;
            const int c16 = ch & 31;
            const int src = half ? sIdr[r] : sIdl[r];
            const uint4 v = *(const uint4*)(c_cur + ((size_t)(b * S_) + src) * H_ + c16 * 8);
            *(uint4*)&Csh[half][r][c16 * 8] = v;
        }
    }
    __syncthreads();

    const int lane = tid & 63;
    const int wave = tid >> 6;
    const int m16 = lane & 15;
    const int q = lane >> 4;

    f32x4 acc[2][4][5];
    const f32x4 z4 = {0.f, 0.f, 0.f, 0.f};
#pragma unroll
    for (int sm = 0; sm < 2; ++sm)
#pragma unroll
        for (int wg = 0; wg < 4; ++wg)
#pragma unroll
            for (int g = 0; g < 5; ++g) acc[sm][wg][g] = z4;

    const __hip_bfloat16* bp_base = Bp + ((size_t)(wave * 320 + m16)) * 32 + q * 8;

    for (int ks = 0; ks < KSL; ++ks) {
        const bf16x8 a0 = *reinterpret_cast<const bf16x8*>(&Ash[m16][ks * 32 + q * 8]);
        const bf16x8 a1 = *reinterpret_cast<const bf16x8*>(&Ash[16 + m16][ks * 32 + q * 8]);
        const __hip_bfloat16* bk = bp_base + (size_t)ks * (NPACK * 32);
#pragma unroll
        for (int wg = 0; wg < 4; ++wg) {
            bf16x8 bfrag[5];
#pragma unroll
            for (int g = 0; g < 5; ++g)
                bfrag[g] = *reinterpret_cast<const bf16x8*>(bk + (wg * 80 + g * 16) * 32);
#pragma unroll
            for (int g = 0; g < 5; ++g) {
                acc[0][wg][g] = __builtin_amdgcn_mfma_f32_16x16x32_bf16(a0, bfrag[g], acc[0][wg][g], 0, 0, 0);
                acc[1][wg][g] = __builtin_amdgcn_mfma_f32_16x16x32_bf16(a1, bfrag[g], acc[1][wg][g], 0, 0, 0);
            }
        }
    }

    // -------- Epilogue (batched loads). Row for slot k: sm=k>>2, j=k&3 -----
    // C layout: col=lane&15, row=q*4+j per 16x16 sub-tile.
    int dloc[8];
    int win8[8];
#pragma unroll
    for (int k = 0; k < 8; ++k) {
        const int r = (k >> 2) * 16 + q * 4 + (k & 3);
        dloc[k] = sIdd[r];
        win8[k] = winner_t[b * S_ + dloc[k]];   // 8 independent random 4B loads
    }

#pragma unroll
    for (int wg = 0; wg < 4; ++wg) {
        const int c = (wave * 4 + wg) * 16 + m16;
        // Batch-issue all 8 x loads unconditionally (one wait, 8 in flight)
        uint2 xp[8];
#pragma unroll
        for (int k = 0; k < 8; ++k) {
            const int r = (k >> 2) * 16 + q * 4 + (k & 3);
            const size_t xbase = ((size_t)(b * S_ + s0 + r)) * 1024;
            xp[k] = *(const uint2*)(x_pack + xbase + (size_t)c * 4);
        }
#pragma unroll
        for (int k = 0; k < 8; ++k) {
            const int sm = k >> 2, j = k & 3;
            const int r = sm * 16 + q * 4 + j;
            const int s = s0 + r;
            const int d = dloc[k];
            if (d == 0) continue;
            if (win8[k] != s) continue;
            union { uint2 u; __hip_bfloat16 x[4]; } xv;
            xv.u = xp[k];
            const float xi = __bfloat162float(xv.x[0]);
            const float xo = __bfloat162float(xv.x[1]);
            const float xu = __bfloat162float(xv.x[2]);
            const float xf = __bfloat162float(xv.x[3]);
            const float ig = sigm(acc[sm][wg][0][j] + xi);
            const float og = sigm(acc[sm][wg][1][j] + xo);
            const float ug = fast_tanh(acc[sm][wg][2][j] + xu);
            const float fl = sigm(acc[sm][wg][3][j] + xf);
            const float fr = sigm(acc[sm][wg][4][j] + xf);
            const float cl = __bfloat162float(Csh[0][r][c]);
            const float cr = __bfloat162float(Csh[1][r][c]);
            const float cn = ig * ug + fl * cl + fr * cr;
            const float hn = og * fast_tanh(cn);
            const size_t orow = ((size_t)(b * S_ + d)) * H_;
            c_next[orow + c] = __float2bfloat16(cn);
            h_next[orow + c] = __float2bfloat16(hn);
        }
    }
}

// ---------------------------------------------------------------------------
// Final h,c bf16 -> fp32 into d_out
// ---------------------------------------------------------------------------
__global__ __launch_bounds__(256) void convert_kernel(
    const __hip_bfloat16* __restrict__ h, const __hip_bfloat16* __restrict__ c,
    float* __restrict__ out_h, float* __restrict__ out_c)
{
    const size_t i = ((size_t)blockIdx.x * 256 + threadIdx.x) * 8;
#pragma unroll
    for (int j = 0; j < 8; ++j) {
        out_h[i + j] = __bfloat162float(h[i + j]);
        out_c[i + j] = __bfloat162float(c[i + j]);
    }
}

// ---------------------------------------------------------------------------
// Root: roots[b] = max_s tree_ids[b, STEPS-1, s]; h_root = h[b, root]
// ---------------------------------------------------------------------------
__global__ __launch_bounds__(256) void root_kernel(
    const int* __restrict__ tree_ids,
    const __hip_bfloat16* __restrict__ h, float* __restrict__ h_root)
{
    const int b = blockIdx.x;
    const int tid = threadIdx.x;
    const int* ids = tree_ids + ((size_t)b * STEPS_ + (STEPS_ - 1)) * S_;
    __shared__ int red[256];
    int m = 0;
    for (int s = tid; s < S_; s += 256) m = max(m, ids[s]);
    red[tid] = m;
    __syncthreads();
    for (int off = 128; off > 0; off >>= 1) {
        if (tid < off) red[tid] = max(red[tid], red[tid + off]);
        __syncthreads();
    }
    const int root = red[0];
    h_root[(size_t)b * H_ + tid] =
        __bfloat162float(h[((size_t)(b * S_) + root) * H_ + tid]);
}

// ---------------------------------------------------------------------------
extern "C" void kernel_launch(void* const* d_in, const int* in_sizes, int n_in,
                              void* d_out, int out_size, void* d_ws, size_t ws_size,
                              hipStream_t stream)
{
    const float* input_ids  = (const float*)d_in[0];
    const int*   tree_ids   = (const int*)d_in[1];
    const int*   tree_ids_r = (const int*)d_in[2];
    const int*   tree_ids_l = (const int*)d_in[3];
    const float* W_iou   = (const float*)d_in[4];
    const float* b_iou   = (const float*)d_in[5];
    const float* U_iou_l = (const float*)d_in[6];
    const float* U_iou_r = (const float*)d_in[7];
    const float* W_f     = (const float*)d_in[8];
    const float* b_f     = (const float*)d_in[9];
    const float* U_f_ll  = (const float*)d_in[10];
    const float* U_f_lr  = (const float*)d_in[11];
    const float* U_f_rl  = (const float*)d_in[12];
    const float* U_f_rr  = (const float*)d_in[13];

    float* out = (float*)d_out;
    float* out_h = out;
    float* out_c = out + (size_t)BS_ * H_;
    float* out_root = out + (size_t)2 * BS_ * H_;

    // ws layout (bytes):
    //   x_pack bf16 [BS][1024]   : 0          .. 134217728
    //   hA     bf16 [BS][256]    : 134217728  .. 167772160
    //   cA     bf16 [BS][256]    : 167772160  .. 201326592
    //   winner int  [24][B][S]   : 201326592  .. 207618048
    //   Bp     bf16 [16][1280][32]: 207618048 .. 208928768
    //   Wp     bf16 [10][1024][32]: 208928768 .. 209584128
    char* ws = (char*)d_ws;
    __hip_bfloat16* x_pack = (__hip_bfloat16*)(ws);
    __hip_bfloat16* hA     = (__hip_bfloat16*)(ws + 134217728ull);
    __hip_bfloat16* cA     = (__hip_bfloat16*)(ws + 167772160ull);
    int*            winner = (int*)(ws + 201326592ull);
    __hip_bfloat16* Bp     = (__hip_bfloat16*)(ws + 207618048ull);
    __hip_bfloat16* Wp     = (__hip_bfloat16*)(ws + 208928768ull);
    // Ping-pong partners live in d_out's h/c regions (fp32-sized, so roomy)
    __hip_bfloat16* hB     = (__hip_bfloat16*)out_h;
    __hip_bfloat16* cB     = (__hip_bfloat16*)out_c;

    hipMemsetAsync(hA, 0, (size_t)BS_ * H_ * sizeof(__hip_bfloat16), stream);
    hipMemsetAsync(cA, 0, (size_t)BS_ * H_ * sizeof(__hip_bfloat16), stream);
    hipMemsetAsync(winner, 0xFF, (size_t)STEPS_ * BS_ * sizeof(int), stream);

    pack_B_kernel<<<(KSL * NPACK * 32 + 255) / 256, 256, 0, stream>>>(
        U_iou_l, U_iou_r, U_f_ll, U_f_lr, U_f_rl, U_f_rr, Bp);
    pack_W_kernel<<<(KSLP * 1024 * 32 + 255) / 256, 256, 0, stream>>>(W_iou, W_f, Wp);
    winner_kernel<<<(B_ * STEPS_ * S_) / 256, 256, 0, stream>>>(tree_ids, winner);
    proj_kernel<<<BS_ / 16, 256, 0, stream>>>(input_ids, Wp, b_iou, b_f, x_pack);

    for (int t = 0; t < STEPS_; ++t) {
        const __hip_bfloat16* hc = (t & 1) ? hB : hA;
        const __hip_bfloat16* cc = (t & 1) ? cB : cA;
        __hip_bfloat16*       hn = (t & 1) ? hA : hB;
        __hip_bfloat16*       cn = (t & 1) ? cA : cB;
        const int* wt = winner + (size_t)t * BS_;

        copy_kernel<<<(BS_ * 8) / 256, 256, 0, stream>>>(
            (const uint4*)hc, (uint4*)hn, (const uint4*)cc, (uint4*)cn, wt);

        step_kernel<<<B_ * (S_ / 32), 256, 0, stream>>>(
            hc, cc, hn, cn, tree_ids, tree_ids_l, tree_ids_r, wt,
            x_pack, Bp, t);
    }

    // t=23 (odd) wrote hA/cA: convert to fp32 into d_out
    convert_kernel<<<(BS_ * H_ / 8) / 256, 256, 0, stream>>>(hA, cA, out_h, out_c);
    root_kernel<<<B_, 256, 0, stream>>>(tree_ids, hA, out_root);
}